// Round 4
// baseline (149.975 us; speedup 1.0000x reference)
//
#include <hip/hip_runtime.h>

// Yoshida 4th-order integrator, Gamma(v) = W @ (U v)^2, B=4096, D=1024, R=256.
// R11: concurrency restructure. R10 counters: MfmaUtil 10%, VALUBusy 9%, HBM
// 20%, occ 31% -> 85% stall, 1 block/CU (LDS 117KB), barriers convoy the whole
// CU. Fix: 8-row tiles, 512 threads, 512 blocks -> TWO independent blocks per
// CU (LDS 68.75KB x2 = 137.5 <= 160; regs ~58 VGPR + 32 acc <= 128 combined at
// 4 waves/SIMD). Cost: MFMA m=16 half-wasted (rows 8-15 zero-padded), MFMA
// work x2 -- acceptable, matrix pipe was 90% idle. Valid rows live in lanes
// l<32; l>=32 lanes compute on zero rows, writes gated. vS/H2S rows 8-15
// zeroed once so fragments read exact zeros.
// Per wave: GEMM A owns n-tiles {2w,2w+1} (A-frags shared), GEMM B owns d-cols
// w*128..w*128+127 (8 tiles, two 4-tile halves, W 2-deep chunked).
// Co-resident blocks b, b+256 pick the SAME packed copy -> shared L2 lines.
// Kept: fp8 e4m3 MFMA path, 4 packed U/W copies, U x8 / W x16 pre-scale,
// pitches 1040/272/1032/1028, force->LDS f16, xacc->LDS f32, U stream
// prefetched across barriers, last-step vS skip, stores fused in s==2.

#define BSZ 4096
#define DD 1024
#define RR 256
#define NCOPY 4
#define COPY_BYTES (512u * 1024u)   // Upk (256KB) + Wpk (256KB) per copy

typedef unsigned char uchar;
typedef long long i64;
typedef __attribute__((ext_vector_type(2))) long i64x2;
typedef __attribute__((ext_vector_type(4))) float f32x4;
typedef __attribute__((ext_vector_type(4))) unsigned int uint4v;
typedef __attribute__((ext_vector_type(4))) _Float16 f16x4;

// pack 4 floats -> 4 fp8 e4m3 bytes (HW cvt, RNE, saturating)
__device__ inline unsigned int f2q4(float a, float b, float c, float d) {
    int lo = __builtin_amdgcn_cvt_pk_fp8_f32(a, b, 0, false);
    int hi = __builtin_amdgcn_cvt_pk_fp8_f32(c, d, lo, true);
    return (unsigned int)hi;
}
__device__ inline uchar f2q1(float x) {
    return (uchar)(__builtin_amdgcn_cvt_pk_fp8_f32(x, x, 0, false) & 0xff);
}

// ---- pack U [R,D] (x8) and W [D,R] (x16) into fragment-major fp8, 4 copies -
// Fragment pair layout: lane l holds 16 bytes = kt=2p (k=kb..kb+7) then
// kt=2p+1 (k=kb+32..kb+39), kb = p*64 + (l>>4)*8; n = tile*16 + (l&15).
__global__ __launch_bounds__(256) void pack_uw_kernel(
    const float* __restrict__ U, const float* __restrict__ W,
    uchar* __restrict__ ws)
{
    const int g = blockIdx.x * 256 + threadIdx.x;
    const float* src;
    size_t off;                         // offset within one copy
    float sc;
    if (g < 16384) {                    // U: 16 nt x 16 p x 64 l
        const int l = g & 63, p = (g >> 6) & 15, nt = g >> 10;
        src = U + (size_t)(nt * 16 + (l & 15)) * DD + p * 64 + (l >> 4) * 8;
        off = ((size_t)nt << 14) + (p << 10) + (l << 4);
        sc = 8.0f;
    } else {                            // W: 64 dtile x 4 p x 64 l
        const int g2 = g - 16384;
        const int l = g2 & 63, p = (g2 >> 6) & 3, dt_ = g2 >> 8;
        src = W + (size_t)(dt_ * 16 + (l & 15)) * RR + p * 64 + (l >> 4) * 8;
        off = (size_t)(256 * 1024) + ((size_t)dt_ << 12) + (p << 10) + (l << 4);
        sc = 16.0f;
    }
    const float4 x0 = *reinterpret_cast<const float4*>(src);
    const float4 x1 = *reinterpret_cast<const float4*>(src + 4);
    const float4 y0 = *reinterpret_cast<const float4*>(src + 32);
    const float4 y1 = *reinterpret_cast<const float4*>(src + 36);
    uint4v o;
    o.x = f2q4(sc * x0.x, sc * x0.y, sc * x0.z, sc * x0.w);
    o.y = f2q4(sc * x1.x, sc * x1.y, sc * x1.z, sc * x1.w);
    o.z = f2q4(sc * y0.x, sc * y0.y, sc * y0.z, sc * y0.w);
    o.w = f2q4(sc * y1.x, sc * y1.y, sc * y1.z, sc * y1.w);
    #pragma unroll
    for (int c = 0; c < NCOPY; ++c)
        *reinterpret_cast<uint4v*>(ws + (size_t)c * COPY_BYTES + off) = o;
}

// ---- fused 3-step integrator, 8 rows/block, 2 blocks/CU --------------------
__global__ __launch_bounds__(512, 2) void yoshida_fused_kernel(
    const float* __restrict__ x_in,
    const float* __restrict__ v_in,
    const float* __restrict__ force,
    const uchar* __restrict__ ws,
    float* __restrict__ x_out,
    float* __restrict__ v_out)
{
    // pitches %128B==16 -> 2-way-max bank aliasing (free per m136)
    __shared__ __align__(16) uchar vS[16][1040];    // rows 8-15 stay zero
    __shared__ __align__(16) uchar H2S[16][272];    // rows 8-15 stay zero
    __shared__ __align__(16) _Float16 fS[8][1032];
    __shared__ __align__(16) float xaS[8][1028];

    const int tid = threadIdx.x;
    const int w = tid >> 6, l = tid & 63;
    const int m = l & 15, q = l >> 4;
    const int b0 = blockIdx.x * 8;
    const int d0 = w * 128;
    const bool act = (l < 32);          // lanes holding valid rows 0..7
    const int rbase = (q & 1) * 4;      // valid row base (dup for q>=2)

    // copy select: co-resident blocks b and b+256 pick the SAME copy
    const uchar* base = ws + (size_t)((blockIdx.x >> 3) & (NCOPY - 1)) * COPY_BYTES;

    constexpr double CBRT2 = 1.2599210498948731647672106072782;
    constexpr double W1c = 1.0 / (2.0 - CBRT2);
    constexpr double W0c = -CBRT2 * W1c;
    constexpr double DTd = 0.01 * 1.0;
    const float dcoef[3] = {(float)(W1c * DTd), (float)(W0c * DTd), (float)(W1c * DTd)};
    const float xcoef[3] = {(float)((W0c + W1c) * 0.5), (float)((W0c + W1c) * 0.5),
                            (float)(W1c * 0.5)};
    const float c1  = (float)(W1c * 0.5);
    const float dtf = (float)DTd;

    // wave w: U n-tiles {2w, 2w+1}; W d-tiles w*8..w*8+7
    const uchar* up = base + ((size_t)(2 * w) << 14) + (l << 4);
    const uchar* wp = base + 256 * 1024 + ((size_t)(w * 8) << 12) + (l << 4);

    // --- stage v row w as fp8; zero row w+8 ---------------------------------
    {
        const float* sp = v_in + (size_t)(b0 + w) * DD + l * 16;
        const float4 f0 = *reinterpret_cast<const float4*>(sp);
        const float4 f1 = *reinterpret_cast<const float4*>(sp + 4);
        const float4 f2 = *reinterpret_cast<const float4*>(sp + 8);
        const float4 f3 = *reinterpret_cast<const float4*>(sp + 12);
        uint4v pk;
        pk.x = f2q4(f0.x, f0.y, f0.z, f0.w);
        pk.y = f2q4(f1.x, f1.y, f1.z, f1.w);
        pk.z = f2q4(f2.x, f2.y, f2.z, f2.w);
        pk.w = f2q4(f3.x, f3.y, f3.z, f3.w);
        *reinterpret_cast<uint4v*>(&vS[w][l * 16]) = pk;
        const uint4v z = {0u, 0u, 0u, 0u};
        *reinterpret_cast<uint4v*>(&vS[w + 8][l * 16]) = z;
    }
    // --- zero H2S rows 8..15 (8 rows x 272B = 136 x 16B) --------------------
    if (tid < 136) {
        const uint4v z = {0u, 0u, 0u, 0u};
        *reinterpret_cast<uint4v*>(&H2S[8 + tid / 17][(tid % 17) * 16]) = z;
    }
    // --- stage force row w as f16 -------------------------------------------
    {
        const float* sp = force + (size_t)(b0 + w) * DD;
        #pragma unroll
        for (int c = 0; c < 4; ++c) {
            const float4 f = *reinterpret_cast<const float4*>(sp + l * 4 + c * 256);
            f16x4 h;
            h.x = (_Float16)f.x; h.y = (_Float16)f.y;
            h.z = (_Float16)f.z; h.w = (_Float16)f.w;
            *reinterpret_cast<f16x4*>(&fS[w][l * 4 + c * 256]) = h;
        }
    }

    // --- per-lane v state: 8 tiles x 4 rows (dup rows for q>=2) -------------
    float vreg[32];
    #pragma unroll
    for (int t = 0; t < 8; ++t)
        #pragma unroll
        for (int i = 0; i < 4; ++i)
            vreg[t * 4 + i] =
                v_in[(size_t)(b0 + rbase + i) * DD + d0 + t * 16 + m];

    // --- U prefetch: p=0 for both n-tiles (in flight across barrier) --------
    i64x2 ub[2][2];
    ub[0][0] = *reinterpret_cast<const i64x2*>(up);
    ub[0][1] = *reinterpret_cast<const i64x2*>(up + 16384);

    #pragma unroll
    for (int s = 0; s < 3; ++s) {
        __syncthreads();   // s==0: vS/fS/H2S-zero staged; s>0: vS rewrites

        // ---- GEMM A: h = (8U).v_q for 2 n-tiles, K=1024, U 2-deep ----------
        f32x4 aA00 = {0.f,0.f,0.f,0.f}, aA01 = {0.f,0.f,0.f,0.f};
        f32x4 aA10 = {0.f,0.f,0.f,0.f}, aA11 = {0.f,0.f,0.f,0.f};
        #pragma unroll
        for (int p = 0; p < 16; ++p) {
            if (p < 15) {
                ub[(p + 1) & 1][0] = *reinterpret_cast<const i64x2*>(up + ((p + 1) << 10));
                ub[(p + 1) & 1][1] = *reinterpret_cast<const i64x2*>(up + 16384 + ((p + 1) << 10));
            } else if (s < 2) {        // next step's p=0: flies over barriers
                ub[0][0] = *reinterpret_cast<const i64x2*>(up);
                ub[0][1] = *reinterpret_cast<const i64x2*>(up + 16384);
            }
            const i64 af0 = *reinterpret_cast<const i64*>(&vS[m][p * 64 + q * 8]);
            const i64 af1 = *reinterpret_cast<const i64*>(&vS[m][p * 64 + 32 + q * 8]);
            aA00 = __builtin_amdgcn_mfma_f32_16x16x32_fp8_fp8(af0, ub[p & 1][0].x, aA00, 0, 0, 0);
            aA01 = __builtin_amdgcn_mfma_f32_16x16x32_fp8_fp8(af1, ub[p & 1][0].y, aA01, 0, 0, 0);
            aA10 = __builtin_amdgcn_mfma_f32_16x16x32_fp8_fp8(af0, ub[p & 1][1].x, aA10, 0, 0, 0);
            aA11 = __builtin_amdgcn_mfma_f32_16x16x32_fp8_fp8(af1, ub[p & 1][1].y, aA11, 0, 0, 0);
        }
        if (act) {
            #pragma unroll
            for (int i = 0; i < 4; ++i) {
                const float h8a = aA00[i] + aA01[i];              // = 8*h, nt=2w
                const float h8b = aA10[i] + aA11[i];              // = 8*h, nt=2w+1
                H2S[q * 4 + i][(2 * w) * 16 + m]     = f2q1(h8a * h8a * 0.015625f);
                H2S[q * 4 + i][(2 * w + 1) * 16 + m] = f2q1(h8b * h8b * 0.015625f);
            }
        }

        // W half-0 chunk p=0 preload (U regs dead; hides L2 latency over bar)
        i64x2 wb[2][4];
        #pragma unroll
        for (int t = 0; t < 4; ++t)
            wb[0][t] = *reinterpret_cast<const i64x2*>(wp + (t << 12));

        __syncthreads();   // H2S published

        // ---- GEMM B: Gamma = (16W).h2_q, K=256, 8 d-tiles in 2 halves ------
        f32x4 accB[8];
        #pragma unroll
        for (int t = 0; t < 8; ++t) accB[t] = (f32x4){0.f, 0.f, 0.f, 0.f};
        #pragma unroll
        for (int h = 0; h < 2; ++h) {
            #pragma unroll
            for (int p = 0; p < 4; ++p) {
                if (p < 3) {
                    #pragma unroll
                    for (int t = 0; t < 4; ++t)
                        wb[(p + 1) & 1][t] = *reinterpret_cast<const i64x2*>(
                            wp + ((h * 4 + t) << 12) + ((p + 1) << 10));
                } else if (h == 0) {   // preload half-1 p=0 into the free slot
                    #pragma unroll
                    for (int t = 0; t < 4; ++t)
                        wb[0][t] = *reinterpret_cast<const i64x2*>(wp + ((4 + t) << 12));
                }
                const i64 ha0 = *reinterpret_cast<const i64*>(&H2S[m][p * 64 + q * 8]);
                const i64 ha1 = *reinterpret_cast<const i64*>(&H2S[m][p * 64 + 32 + q * 8]);
                #pragma unroll
                for (int t = 0; t < 4; ++t) {
                    accB[h * 4 + t] = __builtin_amdgcn_mfma_f32_16x16x32_fp8_fp8(
                                          ha0, wb[p & 1][t].x, accB[h * 4 + t], 0, 0, 0);
                    accB[h * 4 + t] = __builtin_amdgcn_mfma_f32_16x16x32_fp8_fp8(
                                          ha1, wb[p & 1][t].y, accB[h * 4 + t], 0, 0, 0);
                }
            }
        }

        // x_in loads only for s==2 (overlap epilogue; W/U regs dead)
        float xreg[32];
        if (s == 2) {
            #pragma unroll
            for (int t = 0; t < 8; ++t)
                #pragma unroll
                for (int i = 0; i < 4; ++i)
                    xreg[t * 4 + i] =
                        x_in[(size_t)(b0 + rbase + i) * DD + d0 + t * 16 + m];
        }

        // ---- epilogue: v += ddt*f - (ddt/16)*accB; writes gated to l<32 ----
        const float ddt = dcoef[s], cx = xcoef[s], gsc = dcoef[s] * 0.0625f;
        #pragma unroll
        for (int t = 0; t < 8; ++t)
            #pragma unroll
            for (int i = 0; i < 4; ++i) {
                const int r = rbase + i, c = d0 + t * 16 + m;
                const float ff = (float)fS[r][c];
                const float vold = vreg[t * 4 + i];
                const float vn = vold + ddt * ff - gsc * accB[t][i];
                vreg[t * 4 + i] = vn;
                if (act) {
                    if (s == 0) {
                        xaS[r][c] = c1 * vold + cx * vn;
                        vS[r][c] = f2q1(vn);
                    } else if (s == 1) {
                        xaS[r][c] += cx * vn;
                        vS[r][c] = f2q1(vn);
                    } else {
                        const float xa = xaS[r][c] + cx * vn;
                        const size_t g = (size_t)(b0 + r) * DD + c;
                        x_out[g] = xreg[t * 4 + i] + dtf * xa;
                        v_out[g] = vn;
                    }
                }
            }
    }
}

extern "C" void kernel_launch(void* const* d_in, const int* in_sizes, int n_in,
                              void* d_out, int out_size, void* d_ws, size_t ws_size,
                              hipStream_t stream) {
    const float* x     = (const float*)d_in[0];
    const float* v     = (const float*)d_in[1];
    const float* force = (const float*)d_in[2];
    const float* U     = (const float*)d_in[3];
    const float* W     = (const float*)d_in[4];

    float* x_out = (float*)d_out;
    float* v_out = x_out + (size_t)BSZ * DD;

    uchar* ws = (uchar*)d_ws;   // NCOPY x 512KB packed copies (2 MB)

    pack_uw_kernel<<<dim3(128), dim3(256), 0, stream>>>(U, W, ws);
    yoshida_fused_kernel<<<dim3(BSZ / 8), dim3(512), 0, stream>>>(
        x, v, force, ws, x_out, v_out);
}

// Round 5
// 148.473 us; speedup vs baseline: 1.0101x; 1.0101x over previous
//
#include <hip/hip_runtime.h>

// Yoshida 4th-order integrator, Gamma(v) = W @ (U v)^2, B=4096, D=1024, R=256.
// R12: ALGORITHMIC restructure. R4-R11 evidence: the 3-step lockstep kernel is
// stall-bound at ~45us (MfmaUtil 10%, VALUBusy 9%, HBM 20%) because each step
// re-streams 512KB of U/W through latency-exposed loops; every schedule-level
// fix (pipelining R10, 2 blocks/CU R11, regs R8/R9) is exhausted.
// Since Gamma ignores x, the iteration collapses to R-space (256 wide):
//   h = U v, g = U f, M = U W  (M precomputed once, 256x256)
//   h_{s+1} = h_s + dt*d_s*(g - M h2_s),  h2 = h*h
//   v_out = v0 + dt*f - dt*(W P),            P = d1 h2_0 + d2 h2_1 + d3 h2_2
//   x_out = x0 + dt*v0 + dt^2*Se*f - dt^2*(W Q), Q = e1 h2_0 + e2 h2_1 + e3 h2_2
// -> U and W are each streamed ONCE (not 3x); the per-step GEMMs shrink 4x to
// 256-wide with M resident in LDS; ~6 barriers total. All operands bf16
// (old path was fp8 end-to-end -> absmax should drop).
// Fused phases: 1) hT=U vT, gT=U fT (shared U stream, B-frags from LDS);
// 2) two M-GEMMs, all-LDS (M bf16 overlaid on dead vA/fA region);
// 3) W P and W Q (shared W stream) + epilogue with exact f32 v0/x0/f.
// Proven envelopes kept: 1024 thr, <=64 arch VGPR per phase, frag reads all
// linear lane*16B (conflict-free), prefetch rings 4-8 deep, pow2 ring indices.

#define BSZ 4096
#define DD 1024
#define RR 256

// ws layout (1.25MB total; old session used 2MB safely)
#define U_OFF 0u                  // 512KB bf16 U A-frags: (nt*32+p)*1024 + l*16
#define W_OFF (512u * 1024u)      // 512KB bf16 W A-frags: (dt*8+p)*1024 + l*16
#define M_OFF (1024u * 1024u)     // 256KB f32 M[256][256] scratch

typedef unsigned char uchar;
typedef long long i64;
typedef unsigned int uint;
typedef __attribute__((ext_vector_type(4))) float f32x4;
typedef __attribute__((ext_vector_type(4))) uint uint4v;
typedef __attribute__((ext_vector_type(8))) short short8;

__device__ inline uint f2bf1(float x) {
    uint u = __builtin_bit_cast(uint, x);
    return (u + 0x7FFFu + ((u >> 16) & 1u)) >> 16;     // RNE f32->bf16
}
__device__ inline uint f2bf2(float lo, float hi) {
    return f2bf1(lo) | (f2bf1(hi) << 16);
}

// ---- pack U and W into bf16 fragment-major A-frags; zero M scratch ---------
// Fragment: slice(tile,p) = 1KB; lane l holds row=(l&15), k=p*32+(l>>4)*8+j.
__global__ __launch_bounds__(256) void pack_kernel(
    const float* __restrict__ U, const float* __restrict__ W,
    uchar* __restrict__ ws)
{
    const int g = blockIdx.x * 256 + threadIdx.x;       // 0..65535
    *reinterpret_cast<float*>(ws + M_OFF + (size_t)g * 4) = 0.0f;  // zero M

    const int l = g & 63;
    const float* src;
    size_t dst;
    if (g < 32768) {                 // U: 16 nt x 32 p slices
        const int slice = g >> 6, nt = slice >> 5, p = slice & 31;
        src = U + (size_t)(nt * 16 + (l & 15)) * DD + p * 32 + (l >> 4) * 8;
        dst = U_OFF + (size_t)slice * 1024 + l * 16;
    } else {                         // W: 64 dt x 8 p slices
        const int g2 = g - 32768;
        const int slice = g2 >> 6, dt_ = slice >> 3, p = slice & 7;
        src = W + (size_t)(dt_ * 16 + (l & 15)) * RR + p * 32 + (l >> 4) * 8;
        dst = W_OFF + (size_t)slice * 1024 + l * 16;
    }
    const float4 a0 = *reinterpret_cast<const float4*>(src);
    const float4 a1 = *reinterpret_cast<const float4*>(src + 4);
    uint4v o;
    o.x = f2bf2(a0.x, a0.y); o.y = f2bf2(a0.z, a0.w);
    o.z = f2bf2(a1.x, a1.y); o.w = f2bf2(a1.z, a1.w);
    *reinterpret_cast<uint4v*>(ws + dst) = o;
}

// ---- M = U @ W, f32, k-split with atomics (M zeroed by pack_kernel) --------
__global__ __launch_bounds__(1024) void mm_kernel(
    const float* __restrict__ U, const float* __restrict__ W,
    uchar* __restrict__ ws)
{
    float* Mf = reinterpret_cast<float*>(ws + M_OFF);
    const int rt = blockIdx.x >> 4;          // 16-row tile 0..15
    const int kc = blockIdx.x & 15;          // 64-wide k chunk 0..15
    const int rp = threadIdx.x & 255;        // output col
    const int ro = threadIdx.x >> 8;         // row group 0..3
    float acc[4] = {0.f, 0.f, 0.f, 0.f};
    const int kb = kc * 64;
    for (int ks = 0; ks < 8; ++ks) {
        float uv[4][8];
        #pragma unroll
        for (int j = 0; j < 4; ++j) {
            const float* us = U + (size_t)(rt * 16 + ro * 4 + j) * DD + kb + ks * 8;
            const float4 u0 = *reinterpret_cast<const float4*>(us);
            const float4 u1 = *reinterpret_cast<const float4*>(us + 4);
            uv[j][0] = u0.x; uv[j][1] = u0.y; uv[j][2] = u0.z; uv[j][3] = u0.w;
            uv[j][4] = u1.x; uv[j][5] = u1.y; uv[j][6] = u1.z; uv[j][7] = u1.w;
        }
        #pragma unroll
        for (int kk = 0; kk < 8; ++kk) {
            const float wv = W[(size_t)(kb + ks * 8 + kk) * RR + rp];
            #pragma unroll
            for (int j = 0; j < 4; ++j) acc[j] += uv[j][kk] * wv;
        }
    }
    #pragma unroll
    for (int j = 0; j < 4; ++j)
        atomicAdd(Mf + (size_t)(rt * 16 + ro * 4 + j) * RR + rp, acc[j]);
}

// ---- fused integrator ------------------------------------------------------
__global__ __launch_bounds__(1024) void yoshida_fused_kernel(
    const float* __restrict__ x_in,
    const float* __restrict__ v_in,
    const float* __restrict__ force,
    const uchar* __restrict__ ws,
    float* __restrict__ x_out,
    float* __restrict__ v_out)
{
    // [0,128K): phase1 = vA(0..32K)+fA(32..64K); phase2+ = M bf16 frags (128K)
    // [128K..136K): H2B bf16 B-frags; [136K..144K): PB; [144K..152K): QB
    __shared__ __align__(16) uchar lds[152 * 1024];
    uchar* const vA  = lds;
    uchar* const fA  = lds + 32768;
    uchar* const Ml  = lds;                  // overlay after phase 1
    uchar* const H2B = lds + 131072;
    uchar* const PB  = lds + 139264;
    uchar* const QB  = lds + 147456;

    const int tid = threadIdx.x;
    const int w = tid >> 6, l = tid & 63;
    const int m = l & 15, q = l >> 4;
    const int b0 = blockIdx.x * 16;

    constexpr double CBRT2 = 1.2599210498948731647672106072782;
    constexpr double W1c = 1.0 / (2.0 - CBRT2);
    constexpr double W0c = -CBRT2 * W1c;
    constexpr double DTd = 0.01;
    constexpr double D1 = W1c, D2 = W0c, D3 = W1c;
    constexpr double C2c = (W0c + W1c) * 0.5, C4c = W1c * 0.5;
    constexpr double E1 = (C2c + C2c + C4c) * D1;   // (c2+c3+c4)*d1
    constexpr double E2 = (C2c + C4c) * D2;         // (c3+c4)*d2
    constexpr double E3 = C4c * D3;                 // c4*d3
    const float dtf = (float)DTd, dt2 = (float)(DTd * DTd);
    const float se = (float)(E1 + E2 + E3);

    // --- stage vA, fA as bf16 B-frags (wave w -> slices 2w, 2w+1) -----------
    #pragma unroll
    for (int j = 0; j < 2; ++j) {
        const int p = 2 * w + j;
        const size_t so = (size_t)(b0 + m) * DD + p * 32 + q * 8;
        const float4 v0_ = *reinterpret_cast<const float4*>(v_in + so);
        const float4 v1_ = *reinterpret_cast<const float4*>(v_in + so + 4);
        const float4 f0_ = *reinterpret_cast<const float4*>(force + so);
        const float4 f1_ = *reinterpret_cast<const float4*>(force + so + 4);
        uint4v ov, of;
        ov.x = f2bf2(v0_.x, v0_.y); ov.y = f2bf2(v0_.z, v0_.w);
        ov.z = f2bf2(v1_.x, v1_.y); ov.w = f2bf2(v1_.z, v1_.w);
        of.x = f2bf2(f0_.x, f0_.y); of.y = f2bf2(f0_.z, f0_.w);
        of.z = f2bf2(f1_.x, f1_.y); of.w = f2bf2(f1_.z, f1_.w);
        *reinterpret_cast<uint4v*>(vA + (size_t)p * 1024 + l * 16) = ov;
        *reinterpret_cast<uint4v*>(fA + (size_t)p * 1024 + l * 16) = of;
    }

    // --- U prefetch (8-deep ring), flies across the barrier ------------------
    const uchar* const up = ws + U_OFF + ((size_t)w << 15) + l * 16;
    uint4v ub[8];
    #pragma unroll
    for (int p = 0; p < 8; ++p)
        ub[p] = *reinterpret_cast<const uint4v*>(up + ((size_t)p << 10));

    __syncthreads();   // barrier 0: vA/fA staged

    // --- phase 1: hT = U vT, gT = U fT (shared U stream) --------------------
    // C layout: lane holds (col = batch m, rows = R 16w+4q+i)
    f32x4 h = {0.f, 0.f, 0.f, 0.f}, g = {0.f, 0.f, 0.f, 0.f};
    #pragma unroll
    for (int p = 0; p < 32; ++p) {
        const uint4v uc = ub[p & 7];
        if (p < 24)
            ub[p & 7] = *reinterpret_cast<const uint4v*>(up + ((size_t)(p + 8) << 10));
        const short8 ua = __builtin_bit_cast(short8, uc);
        const short8 va = __builtin_bit_cast(short8,
            *reinterpret_cast<const uint4v*>(vA + ((size_t)p << 10) + l * 16));
        const short8 fa = __builtin_bit_cast(short8,
            *reinterpret_cast<const uint4v*>(fA + ((size_t)p << 10) + l * 16));
        h = __builtin_amdgcn_mfma_f32_16x16x32_bf16(ua, va, h, 0, 0, 0);
        g = __builtin_amdgcn_mfma_f32_16x16x32_bf16(ua, fa, g, 0, 0, 0);
    }

    __syncthreads();   // barrier 1: vA/fA dead -> M overlay may begin

    // --- stage M bf16 A-frags into [0,128K) (overlay); 8 items/thread -------
    {
        const float* Mf = reinterpret_cast<const float*>(ws + M_OFF);
        #pragma unroll 4
        for (int rep = 0; rep < 8; ++rep) {
            const int item = tid + rep * 1024;
            const int sl = item >> 6, ll = item & 63;
            const int nt = sl >> 3, p = sl & 7;
            const float* sm = Mf + (size_t)(nt * 16 + (ll & 15)) * RR + p * 32 + (ll >> 4) * 8;
            const float4 a0 = *reinterpret_cast<const float4*>(sm);
            const float4 a1 = *reinterpret_cast<const float4*>(sm + 4);
            uint4v o;
            o.x = f2bf2(a0.x, a0.y); o.y = f2bf2(a0.z, a0.w);
            o.z = f2bf2(a1.x, a1.y); o.w = f2bf2(a1.z, a1.w);
            *reinterpret_cast<uint4v*>(Ml + (size_t)sl * 1024 + ll * 16) = o;
        }
    }

    // --- phase 2: R-space iteration; h2 frag coords for this lane -----------
    const int k0 = 16 * w + 4 * q;                 // lane's 4 R-rows k0..k0+3
    const int p0 = k0 >> 5;
    const int lp = ((k0 & 31) >> 3) * 16 + m;
    const int j0 = k0 & 7;                          // 0 or 4

    f32x4 P, Q;
    {   // s = 0: h2_0, init P/Q, publish h2 B-frags
        float h2[4];
        #pragma unroll
        for (int i = 0; i < 4; ++i) h2[i] = h[i] * h[i];
        #pragma unroll
        for (int i = 0; i < 4; ++i) {
            P[i] = (float)D1 * h2[i];
            Q[i] = (float)E1 * h2[i];
        }
        *reinterpret_cast<uint*>(H2B + (size_t)p0 * 1024 + lp * 16 + j0 * 2)
            = f2bf2(h2[0], h2[1]);
        *reinterpret_cast<uint*>(H2B + (size_t)p0 * 1024 + lp * 16 + j0 * 2 + 4)
            = f2bf2(h2[2], h2[3]);
    }
    __syncthreads();   // barrier 2: Ml + H2B[s=0] ready
    {
        f32x4 acc = {0.f, 0.f, 0.f, 0.f};
        #pragma unroll
        for (int p = 0; p < 8; ++p) {
            const short8 ma = __builtin_bit_cast(short8,
                *reinterpret_cast<const uint4v*>(Ml + (size_t)(w * 8 + p) * 1024 + l * 16));
            const short8 hb = __builtin_bit_cast(short8,
                *reinterpret_cast<const uint4v*>(H2B + ((size_t)p << 10) + l * 16));
            acc = __builtin_amdgcn_mfma_f32_16x16x32_bf16(ma, hb, acc, 0, 0, 0);
        }
        const float cg = (float)(DTd * D1);
        #pragma unroll
        for (int i = 0; i < 4; ++i) h[i] += cg * (g[i] - acc[i]);
    }
    __syncthreads();   // barrier 3: all s=0 reads of H2B done
    {   // s = 1
        float h2[4];
        #pragma unroll
        for (int i = 0; i < 4; ++i) h2[i] = h[i] * h[i];
        #pragma unroll
        for (int i = 0; i < 4; ++i) {
            P[i] += (float)D2 * h2[i];
            Q[i] += (float)E2 * h2[i];
        }
        *reinterpret_cast<uint*>(H2B + (size_t)p0 * 1024 + lp * 16 + j0 * 2)
            = f2bf2(h2[0], h2[1]);
        *reinterpret_cast<uint*>(H2B + (size_t)p0 * 1024 + lp * 16 + j0 * 2 + 4)
            = f2bf2(h2[2], h2[3]);
    }
    __syncthreads();   // barrier 4: H2B[s=1] ready
    {
        f32x4 acc = {0.f, 0.f, 0.f, 0.f};
        #pragma unroll
        for (int p = 0; p < 8; ++p) {
            const short8 ma = __builtin_bit_cast(short8,
                *reinterpret_cast<const uint4v*>(Ml + (size_t)(w * 8 + p) * 1024 + l * 16));
            const short8 hb = __builtin_bit_cast(short8,
                *reinterpret_cast<const uint4v*>(H2B + ((size_t)p << 10) + l * 16));
            acc = __builtin_amdgcn_mfma_f32_16x16x32_bf16(ma, hb, acc, 0, 0, 0);
        }
        const float cg = (float)(DTd * D2);
        #pragma unroll
        for (int i = 0; i < 4; ++i) h[i] += cg * (g[i] - acc[i]);
    }
    {   // s = 2: accumulate only (h_3 never needed)
        float h2[4];
        #pragma unroll
        for (int i = 0; i < 4; ++i) h2[i] = h[i] * h[i];
        #pragma unroll
        for (int i = 0; i < 4; ++i) {
            P[i] += (float)D3 * h2[i];
            Q[i] += (float)E3 * h2[i];
        }
    }
    // publish P, Q as bf16 B-frags
    *reinterpret_cast<uint*>(PB + (size_t)p0 * 1024 + lp * 16 + j0 * 2)     = f2bf2(P[0], P[1]);
    *reinterpret_cast<uint*>(PB + (size_t)p0 * 1024 + lp * 16 + j0 * 2 + 4) = f2bf2(P[2], P[3]);
    *reinterpret_cast<uint*>(QB + (size_t)p0 * 1024 + lp * 16 + j0 * 2)     = f2bf2(Q[0], Q[1]);
    *reinterpret_cast<uint*>(QB + (size_t)p0 * 1024 + lp * 16 + j0 * 2 + 4) = f2bf2(Q[2], Q[3]);

    // --- phase 3 W prefetch (half 1: tiles 4w, 4w+1; 4-deep), over barrier --
    const uchar* const wpb = ws + W_OFF + l * 16;
    uint4v wb[4][2];
    #pragma unroll
    for (int p = 0; p < 4; ++p) {
        wb[p][0] = *reinterpret_cast<const uint4v*>(wpb + (size_t)((4 * w)     * 8 + p) * 1024);
        wb[p][1] = *reinterpret_cast<const uint4v*>(wpb + (size_t)((4 * w + 1) * 8 + p) * 1024);
    }

    __syncthreads();   // barrier 5: PB/QB ready

    // --- phase 3: GammaV^T = W P^T, GammaX^T = W Q^T (shared W stream) ------
    #pragma unroll
    for (int half = 0; half < 2; ++half) {
        const int t0 = 4 * w + half * 2;
        f32x4 aV[2] = {{0.f,0.f,0.f,0.f}, {0.f,0.f,0.f,0.f}};
        f32x4 aX[2] = {{0.f,0.f,0.f,0.f}, {0.f,0.f,0.f,0.f}};
        #pragma unroll
        for (int p = 0; p < 8; ++p) {
            const uint4v c0 = wb[p & 3][0];
            const uint4v c1 = wb[p & 3][1];
            if (p < 4) {            // this half's slices p+4
                wb[p & 3][0] = *reinterpret_cast<const uint4v*>(
                    wpb + (size_t)((t0)     * 8 + p + 4) * 1024);
                wb[p & 3][1] = *reinterpret_cast<const uint4v*>(
                    wpb + (size_t)((t0 + 1) * 8 + p + 4) * 1024);
            } else if (half == 0) { // next half's slices p-4
                wb[p & 3][0] = *reinterpret_cast<const uint4v*>(
                    wpb + (size_t)((t0 + 2) * 8 + (p - 4)) * 1024);
                wb[p & 3][1] = *reinterpret_cast<const uint4v*>(
                    wpb + (size_t)((t0 + 3) * 8 + (p - 4)) * 1024);
            }
            const short8 pb = __builtin_bit_cast(short8,
                *reinterpret_cast<const uint4v*>(PB + ((size_t)p << 10) + l * 16));
            const short8 qb = __builtin_bit_cast(short8,
                *reinterpret_cast<const uint4v*>(QB + ((size_t)p << 10) + l * 16));
            const short8 w0 = __builtin_bit_cast(short8, c0);
            const short8 w1 = __builtin_bit_cast(short8, c1);
            aV[0] = __builtin_amdgcn_mfma_f32_16x16x32_bf16(w0, pb, aV[0], 0, 0, 0);
            aV[1] = __builtin_amdgcn_mfma_f32_16x16x32_bf16(w1, pb, aV[1], 0, 0, 0);
            aX[0] = __builtin_amdgcn_mfma_f32_16x16x32_bf16(w0, qb, aX[0], 0, 0, 0);
            aX[1] = __builtin_amdgcn_mfma_f32_16x16x32_bf16(w1, qb, aX[1], 0, 0, 0);
        }
        // epilogue: lane holds (batch b0+m, D = 16*dtile + 4q + i)
        #pragma unroll
        for (int t = 0; t < 2; ++t) {
            const int d0 = (t0 + t) * 16 + 4 * q;
            #pragma unroll
            for (int i = 0; i < 4; ++i) {
                const size_t gi = (size_t)(b0 + m) * DD + d0 + i;
                const float fv = force[gi];
                const float v0 = v_in[gi];
                const float x0 = x_in[gi];
                v_out[gi] = v0 + dtf * fv - dtf * aV[t][i];
                x_out[gi] = x0 + dtf * v0 + dt2 * se * fv - dt2 * aX[t][i];
            }
        }
    }
}

extern "C" void kernel_launch(void* const* d_in, const int* in_sizes, int n_in,
                              void* d_out, int out_size, void* d_ws, size_t ws_size,
                              hipStream_t stream) {
    const float* x     = (const float*)d_in[0];
    const float* v     = (const float*)d_in[1];
    const float* force = (const float*)d_in[2];
    const float* U     = (const float*)d_in[3];
    const float* W     = (const float*)d_in[4];

    float* x_out = (float*)d_out;
    float* v_out = x_out + (size_t)BSZ * DD;

    uchar* ws = (uchar*)d_ws;   // 1.25MB: U/W bf16 frags + M f32 scratch

    pack_kernel<<<dim3(256), dim3(256), 0, stream>>>(U, W, ws);
    mm_kernel<<<dim3(256), dim3(1024), 0, stream>>>(U, W, ws);
    yoshida_fused_kernel<<<dim3(BSZ / 16), dim3(1024), 0, stream>>>(
        x, v, force, ws, x_out, v_out);
}